// Round 5
// baseline (46.388 us; speedup 1.0000x reference)
//
#include <hip/hip_runtime.h>
#include <hip/hip_bf16.h>

#define B_      4
#define L_      2048
#define NE_     768
#define NOUT_   256     // N_BINS * N_HIDDEN
#define NH_     32
#define NB_     8
#define V_      64
#define VOCAB_  1270
#define NC_     32          // chunks per batch row
#define CS_     64          // L_/NC_
#define BM_     32
#define BN_     128
#define BK_     32
#define NROWS_  8192
#define GRID_MAIN_ 512      // (8192/32 row tiles) x (2 col halves)
#define INV_M_  (1.0f / 4194304.0f) // 1/(B*L*NB*V)
#define INF_    0x7FFFFFFF

typedef float f32x4 __attribute__((ext_vector_type(4)));
typedef short s16x8 __attribute__((ext_vector_type(8)));

__device__ __forceinline__ unsigned short f2bf(float x) {
    union { float f; unsigned u; } c; c.f = x;
    unsigned u = c.u;
    return (unsigned short)((u + 0x7fffu + ((u >> 16) & 1u)) >> 16);   // RNE
}

// ---------------- workspace layout (bytes) ----------------
// [0     , 32768 ) mt        int[B*L]
// [32768 , 65536 ) firstocc  int[B*NC*V]
// [65536 , 458752) W1t       bf16[256][768]
// [458752, 462848) W2t       bf16[64][32]
// [462848, 464896) partials  float[512]
// [464896, 464900) cnt       unsigned

// ---- kernel 1: blocks 0..47 W1t transpose; block 48 W2t + cnt reset;
//                blocks 49..80 mt + firstocc (4 chunks per block)
__global__ void __launch_bounds__(256)
k_prep(const int* __restrict__ task_tokens, const float* __restrict__ W1,
       const float* __restrict__ W2, const int* __restrict__ targets,
       short* __restrict__ W1t, short* __restrict__ W2t,
       int* __restrict__ mt, int* __restrict__ firstocc, unsigned* __restrict__ cnt) {
    __shared__ float tl[64][67];
    __shared__ int   stask[V_];
    __shared__ int   smt[4][CS_];
    const int tid = threadIdx.x;

    if (blockIdx.x < 48) {
        const int tIdx = blockIdx.x;
        const int kt = (tIdx % 12) * 64;
        const int ct = (tIdx / 12) * 64;
        #pragma unroll
        for (int p = 0; p < 4; ++p) {
            int kk = (tid >> 4) + p * 16;
            int cc = (tid & 15) * 4;
            float4 v = *reinterpret_cast<const float4*>(&W1[(kt + kk) * NOUT_ + ct + cc]);
            tl[kk][cc] = v.x; tl[kk][cc + 1] = v.y; tl[kk][cc + 2] = v.z; tl[kk][cc + 3] = v.w;
        }
        __syncthreads();
        #pragma unroll
        for (int p = 0; p < 8; ++p) {
            int oc  = (tid >> 5) + p * 8;
            int ok2 = (tid & 31) * 2;
            unsigned pk = ((unsigned)f2bf(tl[ok2 + 1][oc]) << 16) | f2bf(tl[ok2][oc]);
            *reinterpret_cast<unsigned*>(&W1t[(ct + oc) * NE_ + kt + ok2]) = pk;
        }
        return;
    }
    if (blockIdx.x == 48) {
        if (tid == 0) cnt[0] = 0u;
        #pragma unroll
        for (int q = 0; q < 8; ++q) {
            int i = tid + q * 256;
            int col = i >> 5, j = i & 31;
            W2t[col * NH_ + j] = (short)f2bf(W2[j * V_ + col]);
        }
        return;
    }
    // ---- occ blocks: 4 chunks each ----
    if (tid < V_) stask[tid] = task_tokens[tid];
    __syncthreads();
    const int gi = tid >> 6;
    const int v  = tid & 63;
    const int g  = (blockIdx.x - 49) * 4 + gi;
    const int b  = g >> 5, c = g & 31;
    int t = targets[b * L_ + c * CS_ + v];
    int mval = -1;
    #pragma unroll
    for (int j = 0; j < V_; ++j)
        mval = (stask[j] == t) ? j : mval;
    mt[b * L_ + c * CS_ + v] = mval;
    smt[gi][v] = mval;                          // wave-local
    int first = INF_;
    for (int j = CS_ - 1; j >= 0; --j)
        if (smt[gi][j] == v) first = c * CS_ + j;
    firstocc[(b * NC_ + c) * V_ + v] = first;
}

// ---- kernel 2: fused tte + bf16 MFMA GEMM1(32x128) + MFMA GEMM2 + loss + final
__global__ void __launch_bounds__(512, 4)
k_main(const float* __restrict__ h, const float* __restrict__ age,
       const float* __restrict__ targets_age,
       const int* __restrict__ mt, const int* __restrict__ firstocc,
       const short* __restrict__ W1t, const short* __restrict__ W2t,
       const float* __restrict__ time_bins, float* __restrict__ partials,
       unsigned* __restrict__ cnt, float* __restrict__ out) {
    __shared__ __align__(16) short sA[2][BM_][40];
    __shared__ __align__(16) short sB[2][BN_][40];   // sB[0] reused as sH[4][32][40]
    __shared__ __align__(16) short sW2[V_][40];
    __shared__ float stte[BM_][66];
    __shared__ int   sminI[8][V_];
    __shared__ int   smt[CS_];
    __shared__ float sage[BM_];
    __shared__ float sred[8];
    __shared__ float s2[8];
    __shared__ int   sLast;

    const int tid = threadIdx.x;
    const int w   = tid >> 6;
    const int l   = tid & 63;
    const int l15 = l & 15;
    const int l4  = l >> 4;
    const int rt  = blockIdx.x >> 1;      // row tile
    const int hf  = blockIdx.x & 1;       // col half (bins hf*4..hf*4+3)
    const int r0  = rt * BM_;
    const int b   = r0 >> 11;
    const int pos0 = r0 & (L_ - 1);
    const int c    = pos0 >> 6;           // chunk
    const int off  = pos0 & 63;           // 0 or 32

    // ---- issue first GEMM prefetch ----
    const int arow = tid >> 4;            // 0..31
    const int akc  = tid & 15;
    const int brow = tid >> 2;            // 0..127
    const int bch  = tid & 3;
    const float* hA = &h[(r0 + arow) * NE_ + akc * 2];
    const short* bS = &W1t[(hf * BN_ + brow) * NE_ + bch * 8];
    float2 aReg = *(const float2*)hA;
    s16x8  bReg = *(const s16x8*)bS;

    // ---- stage small stuff ----
    if (tid < CS_)  smt[tid]  = mt[b * L_ + c * CS_ + tid];
    if (tid < BM_)  sage[tid] = age[r0 + tid];
    if (tid < 256) {
        int col = tid >> 2, ch = tid & 3;
        *(s16x8*)&sW2[col][ch * 8] = *(const s16x8*)&W2t[col * NH_ + ch * 8];
    }

    // ---- wave-parallel suffix-min over later chunks ----
    {
        int cur = INF_;
        #pragma unroll
        for (int k = 0; k < 4; ++k) {
            int cc = c + 1 + w + k * 8;
            if (cc < NC_) cur = min(cur, firstocc[(b * NC_ + cc) * V_ + l]);
        }
        sminI[w][l] = cur;
    }
    __syncthreads();

    // ---- inline tte scan ----
    {
        const int v  = l;
        const int rg = w;                 // wave owns 4 rows rg*4..rg*4+3
        int cur = INF_;
        #pragma unroll
        for (int ww = 0; ww < 8; ++ww) cur = min(cur, sminI[ww][v]);
        int* stteI = (int*)stte;
        const int jmin = off + rg * 4;
        for (int j = CS_ - 1; j >= jmin; --j) {
            if (smt[j] == v) cur = c * CS_ + j;
            int br = j - off;
            if ((br >> 2) == rg) stteI[br * 66 + v] = cur;
        }
        #pragma unroll
        for (int jr = 0; jr < 4; ++jr) {
            int br  = rg * 4 + jr;
            int tok = stteI[br * 66 + v];
            float val = -1.0f;
            if (tok != INF_) val = targets_age[b * L_ + tok] - sage[br];
            stte[br][v] = val;
        }
    }

    // ---- stage buf 0 ----
    {
        unsigned pk = ((unsigned)f2bf(aReg.y) << 16) | f2bf(aReg.x);
        *(unsigned*)&sA[0][arow][akc * 2] = pk;
        *(s16x8*)&sB[0][brow][bch * 8] = bReg;
    }
    __syncthreads();

    // ---- GEMM1: double-buffered K loop, 2 MFMA/wave/iter ----
    f32x4 acc[2] = {};
    const int rf  = w & 1;
    const int cf0 = (w >> 1) * 2;
    for (int t = 0; t < NE_ / BK_; ++t) {
        const int cur = t & 1;
        if (t < NE_ / BK_ - 1) {
            int kn = (t + 1) * BK_;
            aReg = *(const float2*)(hA + kn);
            bReg = *(const s16x8*)(bS + kn);
        }
        s16x8 af  = *(const s16x8*)&sA[cur][rf * 16 + l15][l4 * 8];
        s16x8 bf0 = *(const s16x8*)&sB[cur][cf0 * 16 + l15][l4 * 8];
        s16x8 bf1 = *(const s16x8*)&sB[cur][cf0 * 16 + 16 + l15][l4 * 8];
        acc[0] = __builtin_amdgcn_mfma_f32_16x16x32_bf16(af, bf0, acc[0], 0, 0, 0);
        acc[1] = __builtin_amdgcn_mfma_f32_16x16x32_bf16(af, bf1, acc[1], 0, 0, 0);
        if (t < NE_ / BK_ - 1) {
            unsigned pk = ((unsigned)f2bf(aReg.y) << 16) | f2bf(aReg.x);
            *(unsigned*)&sA[cur ^ 1][arow][akc * 2] = pk;
            *(s16x8*)&sB[cur ^ 1][brow][bch * 8] = bReg;
        }
        __syncthreads();
    }

    // ---- hh -> sH (overlaying sB[0]); wave w: bin nb=w>>1, rowfrag rf ----
    short* sH = &sB[0][0][0];             // [4][32][40] == [128][40]
    const int nb = w >> 1;
    #pragma unroll
    for (int cc2 = 0; cc2 < 2; ++cc2)
        #pragma unroll
        for (int jr = 0; jr < 4; ++jr)
            sH[(nb * 32 + rf * 16 + l4 * 4 + jr) * 40 + cc2 * 16 + l15] =
                (short)f2bf(acc[cc2][jr]);
    __syncthreads();

    // ---- GEMM2 + loss: wave owns (bin nb, rowfrag rf), loops 4 col-frags ----
    const int n = hf * 4 + nb;            // global bin
    const float sn = time_bins[n], en = time_bins[n + 1];
    const float wn = en - sn;
    s16x8 a2 = *(const s16x8*)&sH[(nb * 32 + rf * 16 + l15) * 40 + l4 * 8];
    const float lastTA = targets_age[b * L_ + (L_ - 1)];

    float lcv[4];
    #pragma unroll
    for (int jr = 0; jr < 4; ++jr)
        lcv[jr] = lastTA - sage[rf * 16 + l4 * 4 + jr];

    float part = 0.0f;
    const f32x4 zero = {};
    #pragma unroll
    for (int cf2 = 0; cf2 < 4; ++cf2) {
        int v = cf2 * 16 + l15;
        s16x8 b2 = *(const s16x8*)&sW2[v][l4 * 8];
        f32x4 c2 = __builtin_amdgcn_mfma_f32_16x16x32_bf16(a2, b2, zero, 0, 0, 0);
        #pragma unroll
        for (int jr = 0; jr < 4; ++jr) {
            int br = rf * 16 + l4 * 4 + jr;
            float ll = c2[jr];
            float ex = __expf(ll);
            float tv = stte[br][v];
            bool occ = (tv > sn) && (tv <= en);
            float cn = fminf(fmaxf(lcv[jr], 0.0f), wn);
            part += ex * (occ ? tv : cn) - (occ ? ll : 0.0f);
        }
    }

    #pragma unroll
    for (int offs = 32; offs > 0; offs >>= 1) part += __shfl_xor(part, offs);
    if (l == 0) sred[w] = part;
    __syncthreads();
    if (tid == 0) {
        float s = 0.0f;
        #pragma unroll
        for (int i = 0; i < 8; ++i) s += sred[i];
        __hip_atomic_store(&partials[blockIdx.x], s, __ATOMIC_RELEASE, __HIP_MEMORY_SCOPE_AGENT);
        unsigned old = __hip_atomic_fetch_add(cnt, 1u, __ATOMIC_ACQ_REL, __HIP_MEMORY_SCOPE_AGENT);
        sLast = (old == GRID_MAIN_ - 1u);
    }
    __syncthreads();
    if (sLast) {
        float x = __hip_atomic_load(&partials[tid], __ATOMIC_RELAXED, __HIP_MEMORY_SCOPE_AGENT);
        #pragma unroll
        for (int o = 32; o > 0; o >>= 1) x += __shfl_xor(x, o);
        if (l == 0) s2[w] = x;
        __syncthreads();
        if (tid == 0) {
            float s = 0.0f;
            #pragma unroll
            for (int i = 0; i < 8; ++i) s += s2[i];
            out[0] = s * INV_M_;
        }
    }
}

extern "C" void kernel_launch(void* const* d_in, const int* in_sizes, int n_in,
                              void* d_out, int out_size, void* d_ws, size_t ws_size,
                              hipStream_t stream) {
    const float* h           = (const float*)d_in[0];
    const float* age         = (const float*)d_in[1];
    const float* targets_age = (const float*)d_in[2];
    const int*   targets     = (const int*)d_in[3];
    const float* W1          = (const float*)d_in[4];
    const float* W2          = (const float*)d_in[5];
    const int*   task_tokens = (const int*)d_in[6];
    const float* time_bins   = (const float*)d_in[7];
    float* out = (float*)d_out;

    char* ws = (char*)d_ws;
    int*      mt       = (int*)(ws + 0);
    int*      firstocc = (int*)(ws + 32768);
    short*    W1t      = (short*)(ws + 65536);
    short*    W2t      = (short*)(ws + 458752);
    float*    partials = (float*)(ws + 462848);
    unsigned* cnt      = (unsigned*)(ws + 464896);

    hipLaunchKernelGGL(k_prep, dim3(81), dim3(256), 0, stream,
                       task_tokens, W1, W2, targets, W1t, W2t, mt, firstocc, cnt);
    hipLaunchKernelGGL(k_main, dim3(GRID_MAIN_), dim3(512), 0, stream,
                       h, age, targets_age, mt, firstocc, W1t, W2t, time_bins,
                       partials, cnt, out);
}

// Round 6
// 33.402 us; speedup vs baseline: 1.3888x; 1.3888x over previous
//
#include <hip/hip_runtime.h>
#include <hip/hip_bf16.h>

#define B_      4
#define L_      2048
#define NE_     768
#define NOUT_   256     // N_BINS * N_HIDDEN
#define NH_     32
#define NB_     8
#define V_      64
#define VOCAB_  1270
#define NC_     32          // chunks per batch row
#define CS_     64          // L_/NC_
#define BM_     32
#define BK_     32
#define NT_     24          // NE_/BK_
#define DEPTH_  4
#define NROWS_  8192
#define GRID_MAIN_ 256
#define INV_M_  (1.0f / 4194304.0f) // 1/(B*L*NB*V)
#define INF_    0x7FFFFFFF

typedef float f32x4 __attribute__((ext_vector_type(4)));
typedef short s16x8 __attribute__((ext_vector_type(8)));

__device__ __forceinline__ unsigned short f2bf(float x) {
    union { float f; unsigned u; } c; c.f = x;
    unsigned u = c.u;
    return (unsigned short)((u + 0x7fffu + ((u >> 16) & 1u)) >> 16);   // RNE
}

// ---------------- workspace layout (bytes) ----------------
// [0     , 32768 ) mt        int[B*L]
// [32768 , 65536 ) firstocc  int[B*NC*V]
// [65536 , 458752) W1t       bf16[256][768]
// [458752, 462848) W2t       bf16[64][32]
// [462848, 464896) partials  float[512] (256 used)
// [464896, 464900) cnt       unsigned

// ---- kernel 1: blocks 0..47 W1t transpose; block 48 W2t + cnt reset;
//                blocks 49..80 mt + firstocc (4 chunks per block)
__global__ void __launch_bounds__(256)
k_prep(const int* __restrict__ task_tokens, const float* __restrict__ W1,
       const float* __restrict__ W2, const int* __restrict__ targets,
       short* __restrict__ W1t, short* __restrict__ W2t,
       int* __restrict__ mt, int* __restrict__ firstocc, unsigned* __restrict__ cnt) {
    __shared__ float tl[64][67];
    __shared__ int   stask[V_];
    __shared__ int   smt[4][CS_];
    const int tid = threadIdx.x;

    if (blockIdx.x < 48) {
        const int tIdx = blockIdx.x;
        const int kt = (tIdx % 12) * 64;
        const int ct = (tIdx / 12) * 64;
        #pragma unroll
        for (int p = 0; p < 4; ++p) {
            int kk = (tid >> 4) + p * 16;
            int cc = (tid & 15) * 4;
            float4 v = *reinterpret_cast<const float4*>(&W1[(kt + kk) * NOUT_ + ct + cc]);
            tl[kk][cc] = v.x; tl[kk][cc + 1] = v.y; tl[kk][cc + 2] = v.z; tl[kk][cc + 3] = v.w;
        }
        __syncthreads();
        #pragma unroll
        for (int p = 0; p < 8; ++p) {
            int oc  = (tid >> 5) + p * 8;
            int ok2 = (tid & 31) * 2;
            unsigned pk = ((unsigned)f2bf(tl[ok2 + 1][oc]) << 16) | f2bf(tl[ok2][oc]);
            *reinterpret_cast<unsigned*>(&W1t[(ct + oc) * NE_ + kt + ok2]) = pk;
        }
        return;
    }
    if (blockIdx.x == 48) {
        if (tid == 0) cnt[0] = 0u;
        #pragma unroll
        for (int q = 0; q < 8; ++q) {
            int i = tid + q * 256;
            int col = i >> 5, j = i & 31;
            W2t[col * NH_ + j] = (short)f2bf(W2[j * V_ + col]);
        }
        return;
    }
    // ---- occ blocks: 4 chunks each ----
    if (tid < V_) stask[tid] = task_tokens[tid];
    __syncthreads();
    const int gi = tid >> 6;
    const int v  = tid & 63;
    const int g  = (blockIdx.x - 49) * 4 + gi;
    const int b  = g >> 5, c = g & 31;
    int t = targets[b * L_ + c * CS_ + v];
    int mval = -1;
    #pragma unroll
    for (int j = 0; j < V_; ++j)
        mval = (stask[j] == t) ? j : mval;
    mt[b * L_ + c * CS_ + v] = mval;
    smt[gi][v] = mval;                          // wave-local
    int first = INF_;
    for (int j = CS_ - 1; j >= 0; --j)
        if (smt[gi][j] == v) first = c * CS_ + j;
    firstocc[(b * NC_ + c) * V_ + v] = first;
}

// ---- kernel 2: fused tte + depth-4 pipelined bf16 MFMA GEMM1(32x256) +
//                MFMA GEMM2 + loss + last-block final reduce
__global__ void __launch_bounds__(512, 2)
k_main(const float* __restrict__ h, const float* __restrict__ age,
       const float* __restrict__ targets_age,
       const int* __restrict__ mt, const int* __restrict__ firstocc,
       const short* __restrict__ W1t, const short* __restrict__ W2t,
       const float* __restrict__ time_bins, float* __restrict__ partials,
       unsigned* __restrict__ cnt, float* __restrict__ out) {
    __shared__ __align__(16) short sA[2][BM_][40];
    __shared__ __align__(16) short sB[2][256][40];   // sB[0] reused as sH[8][32][40]
    __shared__ __align__(16) short sW2[V_][40];
    __shared__ float stte[BM_][66];
    __shared__ int   sminI[8][V_];
    __shared__ int   smt[CS_];
    __shared__ float sage[BM_];
    __shared__ float sred[8];
    __shared__ float s2[4];
    __shared__ int   sLast;

    const int tid = threadIdx.x;
    const int w   = tid >> 6;
    const int l   = tid & 63;
    const int l15 = l & 15;
    const int l4  = l >> 4;
    const int r0  = blockIdx.x * BM_;
    const int b   = r0 >> 11;
    const int pos0 = r0 & (L_ - 1);
    const int c    = pos0 >> 6;           // chunk
    const int off  = pos0 & 63;           // 0 or 32

    // ---- issue warmup loads: tiles 0..3 into slots 0..3 ----
    const int arow = tid >> 4;            // 0..31
    const int akc  = tid & 15;
    const int brow = tid >> 2;            // 0..127
    const int bch  = tid & 3;
    const float* hA  = &h[(r0 + arow) * NE_ + akc * 2];
    const short* bS0 = &W1t[brow * NE_ + bch * 8];
    const short* bS1 = &W1t[(brow + 128) * NE_ + bch * 8];

    float2 aR[DEPTH_];
    s16x8  bR0[DEPTH_], bR1[DEPTH_];
    #pragma unroll
    for (int p = 0; p < DEPTH_; ++p) {
        aR[p]  = *(const float2*)(hA + p * BK_);
        bR0[p] = *(const s16x8*)(bS0 + p * BK_);
        bR1[p] = *(const s16x8*)(bS1 + p * BK_);
    }

    // ---- stage small stuff (overlaps warmup loads) ----
    if (tid < CS_)  smt[tid]  = mt[b * L_ + c * CS_ + tid];
    if (tid < BM_)  sage[tid] = age[r0 + tid];
    if (tid < 256) {
        int col = tid >> 2, ch = tid & 3;
        *(s16x8*)&sW2[col][ch * 8] = *(const s16x8*)&W2t[col * NH_ + ch * 8];
    }

    // ---- wave-parallel suffix-min over later chunks ----
    {
        int cur = INF_;
        #pragma unroll
        for (int k = 0; k < 4; ++k) {
            int cc = c + 1 + w + k * 8;
            if (cc < NC_) cur = min(cur, firstocc[(b * NC_ + cc) * V_ + l]);
        }
        sminI[w][l] = cur;
    }
    __syncthreads();

    // ---- inline tte scan ----
    {
        const int v  = l;
        const int rg = w;                 // wave owns 4 rows rg*4..rg*4+3
        int cur = INF_;
        #pragma unroll
        for (int ww = 0; ww < 8; ++ww) cur = min(cur, sminI[ww][v]);
        int* stteI = (int*)stte;
        const int jmin = off + rg * 4;
        for (int j = CS_ - 1; j >= jmin; --j) {
            if (smt[j] == v) cur = c * CS_ + j;
            int br = j - off;
            if ((br >> 2) == rg) stteI[br * 66 + v] = cur;
        }
        #pragma unroll
        for (int jr = 0; jr < 4; ++jr) {
            int br  = rg * 4 + jr;
            int tok = stteI[br * 66 + v];
            float val = -1.0f;
            if (tok != INF_) val = targets_age[b * L_ + tok] - sage[br];
            stte[br][v] = val;
        }
    }

    // ---- write tile 0 (slot 0), raw barrier ----
    {
        unsigned pk = ((unsigned)f2bf(aR[0].y) << 16) | f2bf(aR[0].x);
        *(unsigned*)&sA[0][arow][akc * 2] = pk;
        *(s16x8*)&sB[0][brow][bch * 8]       = bR0[0];
        *(s16x8*)&sB[0][brow + 128][bch * 8] = bR1[0];
    }
    asm volatile("s_waitcnt lgkmcnt(0)" ::: "memory");
    __builtin_amdgcn_s_barrier();
    asm volatile("" ::: "memory");

    // ---- GEMM1: depth-4 pipelined K loop, fully unrolled, 1 raw barrier/iter ----
    f32x4 acc[2][2] = {};
    #pragma unroll
    for (int t = 0; t < NT_; ++t) {
        const int cur   = t & 1;
        const int slot  = t & 3;
        const int nslot = (t + 1) & 3;
        // prefetch tile t+4 into the slot just freed (consumed by ds_write at t-1)
        if (t < NT_ - DEPTH_) {
            aR[slot]  = *(const float2*)(hA + (t + DEPTH_) * BK_);
            bR0[slot] = *(const s16x8*)(bS0 + (t + DEPTH_) * BK_);
            bR1[slot] = *(const s16x8*)(bS1 + (t + DEPTH_) * BK_);
        }
        // fragments + MFMA on tile t
        s16x8 af0 = *(const s16x8*)&sA[cur][l15][l4 * 8];
        s16x8 af1 = *(const s16x8*)&sA[cur][16 + l15][l4 * 8];
        s16x8 bf0 = *(const s16x8*)&sB[cur][w * 32 + l15][l4 * 8];
        s16x8 bf1 = *(const s16x8*)&sB[cur][w * 32 + 16 + l15][l4 * 8];
        acc[0][0] = __builtin_amdgcn_mfma_f32_16x16x32_bf16(af0, bf0, acc[0][0], 0, 0, 0);
        acc[0][1] = __builtin_amdgcn_mfma_f32_16x16x32_bf16(af0, bf1, acc[0][1], 0, 0, 0);
        acc[1][0] = __builtin_amdgcn_mfma_f32_16x16x32_bf16(af1, bf0, acc[1][0], 0, 0, 0);
        acc[1][1] = __builtin_amdgcn_mfma_f32_16x16x32_bf16(af1, bf1, acc[1][1], 0, 0, 0);
        // write tile t+1 into the other buffer (loads done ~3 iters ago)
        if (t < NT_ - 1) {
            unsigned pk = ((unsigned)f2bf(aR[nslot].y) << 16) | f2bf(aR[nslot].x);
            *(unsigned*)&sA[cur ^ 1][arow][akc * 2] = pk;
            *(s16x8*)&sB[cur ^ 1][brow][bch * 8]       = bR0[nslot];
            *(s16x8*)&sB[cur ^ 1][brow + 128][bch * 8] = bR1[nslot];
        }
        asm volatile("s_waitcnt lgkmcnt(0)" ::: "memory");
        __builtin_amdgcn_s_barrier();
        asm volatile("" ::: "memory");
    }

    // ---- hh -> sH (overlaying sB[0]); wave w owns bin n = w ----
    short (*sH)[BM_][40] = (short (*)[BM_][40])&sB[0][0][0];
    #pragma unroll
    for (int rf2 = 0; rf2 < 2; ++rf2)
        #pragma unroll
        for (int cfg = 0; cfg < 2; ++cfg) {
            int jj = cfg * 16 + l15;
            #pragma unroll
            for (int jr = 0; jr < 4; ++jr)
                sH[w][rf2 * 16 + l4 * 4 + jr][jj] = (short)f2bf(acc[rf2][cfg][jr]);
        }
    __syncthreads();

    // ---- GEMM2 + loss: wave owns (rf = w&1, cf = w>>1), loops all 8 bins ----
    const int rf = w & 1;
    const int cf = w >> 1;
    const int v  = cf * 16 + l15;
    s16x8 b2 = *(const s16x8*)&sW2[v][l4 * 8];

    float tb[NB_ + 1];
    #pragma unroll
    for (int n = 0; n <= NB_; ++n) tb[n] = time_bins[n];

    float tva[4], lcv[4];
    const float lastTA = targets_age[b * L_ + (L_ - 1)];
    #pragma unroll
    for (int jr = 0; jr < 4; ++jr) {
        int br = rf * 16 + l4 * 4 + jr;
        tva[jr] = stte[br][v];
        lcv[jr] = lastTA - sage[br];
    }

    float part = 0.0f;
    const f32x4 zero = {};
    #pragma unroll
    for (int n = 0; n < NB_; ++n) {
        s16x8 a2 = *(const s16x8*)&sH[n][rf * 16 + l15][l4 * 8];
        f32x4 c2 = __builtin_amdgcn_mfma_f32_16x16x32_bf16(a2, b2, zero, 0, 0, 0);
        float sn = tb[n], en = tb[n + 1], wn = en - sn;
        #pragma unroll
        for (int jr = 0; jr < 4; ++jr) {
            float ll = c2[jr];
            float ex = __expf(ll);
            float tv = tva[jr];
            bool occ = (tv > sn) && (tv <= en);
            float cn = fminf(fmaxf(lcv[jr], 0.0f), wn);
            part += ex * (occ ? tv : cn) - (occ ? ll : 0.0f);
        }
    }

    #pragma unroll
    for (int offs = 32; offs > 0; offs >>= 1) part += __shfl_xor(part, offs);
    if (l == 0) sred[w] = part;
    __syncthreads();
    if (tid == 0) {
        float s = 0.0f;
        #pragma unroll
        for (int i = 0; i < 8; ++i) s += sred[i];
        __hip_atomic_store(&partials[blockIdx.x], s, __ATOMIC_RELEASE, __HIP_MEMORY_SCOPE_AGENT);
        unsigned old = __hip_atomic_fetch_add(cnt, 1u, __ATOMIC_ACQ_REL, __HIP_MEMORY_SCOPE_AGENT);
        sLast = (old == GRID_MAIN_ - 1u);
    }
    __syncthreads();
    if (sLast) {
        float x = 0.0f;
        if (tid < 256)
            x = __hip_atomic_load(&partials[tid], __ATOMIC_RELAXED, __HIP_MEMORY_SCOPE_AGENT);
        #pragma unroll
        for (int o = 32; o > 0; o >>= 1) x += __shfl_xor(x, o);
        if (tid < 256 && (tid & 63) == 0) s2[tid >> 6] = x;
        __syncthreads();
        if (tid == 0) out[0] = (s2[0] + s2[1] + s2[2] + s2[3]) * INV_M_;
    }
}

extern "C" void kernel_launch(void* const* d_in, const int* in_sizes, int n_in,
                              void* d_out, int out_size, void* d_ws, size_t ws_size,
                              hipStream_t stream) {
    const float* h           = (const float*)d_in[0];
    const float* age         = (const float*)d_in[1];
    const float* targets_age = (const float*)d_in[2];
    const int*   targets     = (const int*)d_in[3];
    const float* W1          = (const float*)d_in[4];
    const float* W2          = (const float*)d_in[5];
    const int*   task_tokens = (const int*)d_in[6];
    const float* time_bins   = (const float*)d_in[7];
    float* out = (float*)d_out;

    char* ws = (char*)d_ws;
    int*      mt       = (int*)(ws + 0);
    int*      firstocc = (int*)(ws + 32768);
    short*    W1t      = (short*)(ws + 65536);
    short*    W2t      = (short*)(ws + 458752);
    float*    partials = (float*)(ws + 462848);
    unsigned* cnt      = (unsigned*)(ws + 464896);

    hipLaunchKernelGGL(k_prep, dim3(81), dim3(256), 0, stream,
                       task_tokens, W1, W2, targets, W1t, W2t, mt, firstocc, cnt);
    hipLaunchKernelGGL(k_main, dim3(GRID_MAIN_), dim3(512), 0, stream,
                       h, age, targets_age, mt, firstocc, W1t, W2t, time_bins,
                       partials, cnt, out);
}